// Round 4
// baseline (454.640 us; speedup 1.0000x reference)
//
#include <hip/hip_runtime.h>
#include <hip/hip_bf16.h>
#include <math.h>

#define E_EDGES 500000
#define PI_F 3.14159265358979323846f
#define TWOPI_F 6.28318530717958647692f

typedef __attribute__((ext_vector_type(4))) float f32x4;
typedef __attribute__((ext_vector_type(8))) short s16x8;

static __device__ __forceinline__ short f2bf(float x) {
    __hip_bfloat16 h = __float2bfloat16(x);
    return __builtin_bit_cast(short, h);
}

// ---------------- prep: W1/W2 -> bf16 fragment-slot layout in ws -------------
// Per d: 24 slots x 128 s16x8 (49152 B).
//   slots 0..7  : W1^T, kb = (sg>>2)*32 + (sg&3)*4   (k=64 row excluded)
//   slots 8..23 : W2^T, same pattern
// Entry j elems: bf16 of W[(kb+i)*128+j] (i=0..3) and W[(kb+16+i)*128+j] (4..7).
__global__ void rape_prep_kernel(const float* __restrict__ W1,
                                 const float* __restrict__ W2,
                                 s16x8* __restrict__ ws)
{
    const int d  = blockIdx.x / 24;
    const int sg = blockIdx.x % 24;
    const int j  = threadIdx.x;            // 0..127
    s16x8 v;
    if (sg < 8) {
        const float* W1d = W1 + (size_t)d * 65 * 128;
        const int kb = (sg >> 2) * 32 + (sg & 3) * 4;
        #pragma unroll
        for (int i = 0; i < 4; ++i) {
            v[i]     = f2bf(W1d[(kb + i) * 128 + j]);
            v[i + 4] = f2bf(W1d[(kb + 16 + i) * 128 + j]);
        }
    } else {
        const int sg2 = sg - 8;
        const float* W2d = W2 + (size_t)d * 128 * 128;
        const int kb = (sg2 >> 2) * 32 + (sg2 & 3) * 4;
        #pragma unroll
        for (int i = 0; i < 4; ++i) {
            v[i]     = f2bf(W2d[(kb + i) * 128 + j]);
            v[i + 4] = f2bf(W2d[(kb + 16 + i) * 128 + j]);
        }
    }
    ws[(size_t)d * 24 * 128 + sg * 128 + j] = v;
}

// ---------------- main fused kernel ------------------------------------------
// Block = 512 thr = 8 waves, 256 edges (32/wave, es=2 x 16). One 48 KB slab
// stage per d serves all 8 waves. Small params LDS-resident for the whole
// block (R2-proven). k=64 passthrough folded into d1 init as fp32 FMA.
__global__ __launch_bounds__(512, 4)
void rape_mfma3_kernel(const float* __restrict__ source,
                       const float* __restrict__ target,
                       const int*   __restrict__ edge,
                       const float* __restrict__ freqs,
                       const float* __restrict__ W1,
                       const float* __restrict__ b1,
                       const float* __restrict__ ln_w,
                       const float* __restrict__ ln_b,
                       const float* __restrict__ b2,
                       const s16x8* __restrict__ wsg,
                       float* __restrict__ out)
{
    __shared__ s16x8 slab[24 * 128];      // 49152 B, restaged per d
    __shared__ float feat_s[6][256];      // 6144 B
    __shared__ float b1_s[768];           // [d][j]
    __shared__ float lnw_s[768];
    __shared__ float lnb_s[768];
    __shared__ float w164_s[768];         // W1[d][64][j]
    __shared__ float freq_s[192];

    const int tid   = threadIdx.x;
    const int lane  = tid & 63;
    const int wv    = tid >> 6;           // wave 0..7
    const int c     = lane & 15;          // edge-col within 16
    const int g     = lane >> 4;          // k-group 0..3
    const int ebase = blockIdx.x * 256;

    // ---- one-time staging: params + features ----
    for (int i = tid; i < 768; i += 512) {
        b1_s[i]   = b1[i];
        lnw_s[i]  = ln_w[i];
        lnb_s[i]  = ln_b[i];
        w164_s[i] = W1[((size_t)(i >> 7) * 65 + 64) * 128 + (i & 127)];
    }
    if (tid < 192) freq_s[tid] = freqs[tid];

    if (tid < 256) {
        int ec = ebase + tid; if (ec >= E_EDGES) ec = E_EDGES - 1;
        int si = edge[ec];
        int ti = edge[E_EDGES + ec];
        const float* S = source + (size_t)si * 5;
        const float* T = target + (size_t)ti * 5;
        float spx = S[0], spy = S[1], shd = S[2], ss = S[3];
        float tpx = T[0], tpy = T[1], thd = T[2], ts = T[3];
        float dx = spx - tpx, dy = spy - tpy;
        float dist = sqrtf(dx * dx + dy * dy);
        float ic  = dist < 3.0f ? 1.0f : 0.0f;
        float inv = dist > 0.0f ? 1.0f / dist : 0.0f;
        float ca  = dist > 0.0f ? dx * inv : 1.0f;   // cos(atan2), atan2(0,0)=0
        float sa  = dy * inv;
        float a = shd - thd + PI_F;
        float r = fmodf(a, TWOPI_F);
        r = r < 0.0f ? r + TWOPI_F : r;
        float dh = r - PI_F;
        float tc = ts * (cosf(thd) * ca + sinf(thd) * sa);
        float sc = ss * (cosf(shd) * ca + sinf(shd) * sa);
        feat_s[0][tid] = dx; feat_s[1][tid] = dy; feat_s[2][tid] = dh;
        feat_s[3][tid] = ic; feat_s[4][tid] = tc; feat_s[5][tid] = sc;
    }

    // ---- acc init: sum_d b2[d][g'],  g' = 4g + q + 16gt (global, once) ----
    f32x4 acc[2][8];
    #pragma unroll
    for (int gt = 0; gt < 8; ++gt) {
        f32x4 s = {0.f, 0.f, 0.f, 0.f};
        #pragma unroll
        for (int d = 0; d < 6; ++d)
            s += *(const f32x4*)(b2 + d * 128 + gt * 16 + g * 4);
        acc[0][gt] = s; acc[1][gt] = s;
    }

    for (int d = 0; d < 6; ++d) {
        __syncthreads();   // prev-d fragment reads done; d=0: params/feat visible

        // ---- stage this d's slab: 49152 B linear copy via global_load_lds ----
        {
            const char* gsrc = (const char*)(wsg + (size_t)d * 24 * 128);
            #pragma unroll
            for (int it = 0; it < 6; ++it) {
                const int off = tid * 16 + it * 8192;
                __builtin_amdgcn_global_load_lds(
                    (const __attribute__((address_space(1))) unsigned int*)(gsrc + off),
                    (__attribute__((address_space(3))) unsigned int*)((char*)slab + off),
                    16, 0, 0);
            }
        }

        // ---- m1 B-frags from trig while staging flies ----
        // k = 32*ks + 4g + q + 16p ; elem i<4 -> p=0, i>=4 -> p=1
        s16x8 bfr[2][2];
        float xv[2];
        const f32x4 fq0 = *(const f32x4*)(freq_s + d * 32 + g * 4);
        const f32x4 fq1 = *(const f32x4*)(freq_s + d * 32 + 16 + g * 4);
        #pragma unroll
        for (int es = 0; es < 2; ++es) {
            const float x = feat_s[d][wv * 32 + es * 16 + c];
            xv[es] = x;
            s16x8 bc, bs;
            #pragma unroll
            for (int i = 0; i < 8; ++i) {
                const float f = (i < 4) ? fq0[i] : fq1[i - 4];
                const float t = x * f;
                const float tf = t - floorf(t);
                bc[i] = f2bf(__builtin_amdgcn_cosf(tf));  // cos(2*pi*t)
                bs[i] = f2bf(__builtin_amdgcn_sinf(tf));
            }
            bfr[es][0] = bc; bfr[es][1] = bs;
        }

        // ---- d1 init: b1 + x * W1[k=64] (fp32 passthrough, from LDS) ----
        f32x4 d1[2][8];
        #pragma unroll
        for (int jt = 0; jt < 8; ++jt) {
            const f32x4 bv  = *(const f32x4*)(b1_s   + d * 128 + jt * 16 + g * 4);
            const f32x4 wv4 = *(const f32x4*)(w164_s + d * 128 + jt * 16 + g * 4);
            d1[0][jt] = bv + xv[0] * wv4;
            d1[1][jt] = bv + xv[1] * wv4;
        }

        __syncthreads();   // slab staged (vmcnt drained at barrier)

        // ---- m1: D1'[j][e] += sum_{k<64} W1^T[j][k] * X^T[k][e] ----
        #pragma unroll
        for (int jt = 0; jt < 8; ++jt) {
            const s16x8 a0 = slab[(0 + g) * 128 + jt * 16 + c];
            const s16x8 a1 = slab[(4 + g) * 128 + jt * 16 + c];
            #pragma unroll
            for (int es = 0; es < 2; ++es) {
                d1[es][jt] = __builtin_amdgcn_mfma_f32_16x16x32_bf16(a0, bfr[es][0], d1[es][jt], 0, 0, 0);
                d1[es][jt] = __builtin_amdgcn_mfma_f32_16x16x32_bf16(a1, bfr[es][1], d1[es][jt], 0, 0, 0);
            }
        }

        // ---- LayerNorm stats (lane holds j = 4g+q+16jt) ----
        float mu[2], rinv[2];
        #pragma unroll
        for (int es = 0; es < 2; ++es) {
            float s1 = 0.f, s2 = 0.f;
            #pragma unroll
            for (int jt = 0; jt < 8; ++jt)
                #pragma unroll
                for (int q = 0; q < 4; ++q) {
                    const float v = d1[es][jt][q];
                    s1 += v; s2 = fmaf(v, v, s2);
                }
            s1 += __shfl_xor(s1, 16); s1 += __shfl_xor(s1, 32);
            s2 += __shfl_xor(s2, 16); s2 += __shfl_xor(s2, 32);
            mu[es] = s1 * 0.0078125f;
            const float var = s2 * 0.0078125f - mu[es] * mu[es];
            rinv[es] = rsqrtf(var + 1e-5f);
        }
        // ---- LN apply + ReLU + pack (lw/lb read once, applied to both es) ----
        s16x8 pb[2][4];
        #pragma unroll
        for (int ks = 0; ks < 4; ++ks) {
            #pragma unroll
            for (int p = 0; p < 2; ++p) {
                const int jt = 2 * ks + p;
                const f32x4 lw = *(const f32x4*)(lnw_s + d * 128 + jt * 16 + g * 4);
                const f32x4 lb = *(const f32x4*)(lnb_s + d * 128 + jt * 16 + g * 4);
                #pragma unroll
                for (int es = 0; es < 2; ++es) {
                    #pragma unroll
                    for (int q = 0; q < 4; ++q) {
                        float hv = (d1[es][jt][q] - mu[es]) * rinv[es];
                        hv = fmaf(hv, lw[q], lb[q]);
                        hv = fmaxf(hv, 0.f);
                        pb[es][ks][q + 4 * p] = f2bf(hv);   // m2 B-frag (k=j)
                    }
                }
            }
        }

        // ---- m2: acc[g'][e] += sum_j W2^T[g'][j] * H'[j][e] ----
        #pragma unroll
        for (int gt = 0; gt < 8; ++gt) {
            const s16x8 a0 = slab[(8 + 0 * 4 + g) * 128 + gt * 16 + c];
            const s16x8 a1 = slab[(8 + 1 * 4 + g) * 128 + gt * 16 + c];
            const s16x8 a2 = slab[(8 + 2 * 4 + g) * 128 + gt * 16 + c];
            const s16x8 a3 = slab[(8 + 3 * 4 + g) * 128 + gt * 16 + c];
            #pragma unroll
            for (int es = 0; es < 2; ++es) {
                acc[es][gt] = __builtin_amdgcn_mfma_f32_16x16x32_bf16(a0, pb[es][0], acc[es][gt], 0, 0, 0);
                acc[es][gt] = __builtin_amdgcn_mfma_f32_16x16x32_bf16(a1, pb[es][1], acc[es][gt], 0, 0, 0);
                acc[es][gt] = __builtin_amdgcn_mfma_f32_16x16x32_bf16(a2, pb[es][2], acc[es][gt], 0, 0, 0);
                acc[es][gt] = __builtin_amdgcn_mfma_f32_16x16x32_bf16(a3, pb[es][3], acc[es][gt], 0, 0, 0);
            }
        }
    }

    // ---- store: lane holds g' = 4g + q + 16gt of edges (wv*32 + es*16 + c) ----
    #pragma unroll
    for (int es = 0; es < 2; ++es) {
        const int e = ebase + wv * 32 + es * 16 + c;
        if (e < E_EDGES) {
            float* op = out + (size_t)e * 128 + g * 4;
            #pragma unroll
            for (int gt = 0; gt < 8; ++gt)
                *(f32x4*)(op + gt * 16) = acc[es][gt];
        }
    }
}

extern "C" void kernel_launch(void* const* d_in, const int* in_sizes, int n_in,
                              void* d_out, int out_size, void* d_ws, size_t ws_size,
                              hipStream_t stream) {
    const float* source = (const float*)d_in[0];
    const float* target = (const float*)d_in[1];
    const int*   edge   = (const int*)  d_in[2];
    const float* freqs  = (const float*)d_in[3];
    const float* W1     = (const float*)d_in[4];
    const float* b1     = (const float*)d_in[5];
    const float* ln_w   = (const float*)d_in[6];
    const float* ln_b   = (const float*)d_in[7];
    const float* W2     = (const float*)d_in[8];
    const float* b2     = (const float*)d_in[9];
    float* out = (float*)d_out;
    s16x8* wsg = (s16x8*)d_ws;    // needs 6*24*128*16 = 294912 B

    rape_prep_kernel<<<6 * 24, 128, 0, stream>>>(W1, W2, wsg);

    const int nblocks = (E_EDGES + 255) / 256;  // 1954
    rape_mfma3_kernel<<<nblocks, 512, 0, stream>>>(
        source, target, edge, freqs, W1, b1, ln_w, ln_b, b2, wsg, out);
}

// Round 5
// 243.760 us; speedup vs baseline: 1.8651x; 1.8651x over previous
//
#include <hip/hip_runtime.h>
#include <hip/hip_bf16.h>
#include <math.h>

#define E_EDGES 500000
#define PI_F 3.14159265358979323846f
#define TWOPI_F 6.28318530717958647692f

typedef __attribute__((ext_vector_type(4))) float f32x4;
typedef __attribute__((ext_vector_type(8))) short s16x8;

static __device__ __forceinline__ short f2bf(float x) {
    __hip_bfloat16 h = __float2bfloat16(x);
    return __builtin_bit_cast(short, h);
}

// ---------------- prep: W1/W2 -> bf16 fragment-slot layout in ws -------------
// Per d: 24 slots x 128 s16x8 (49152 B).
//   slots 0..7  : W1^T, kb = (sg>>2)*32 + (sg&3)*4   (k=64 row excluded)
//   slots 8..23 : W2^T, same pattern
// Entry j elems: bf16 of W[(kb+i)*128+j] (i=0..3) and W[(kb+16+i)*128+j] (4..7).
__global__ void rape_prep_kernel(const float* __restrict__ W1,
                                 const float* __restrict__ W2,
                                 s16x8* __restrict__ ws)
{
    const int d  = blockIdx.x / 24;
    const int sg = blockIdx.x % 24;
    const int j  = threadIdx.x;            // 0..127
    s16x8 v;
    if (sg < 8) {
        const float* W1d = W1 + (size_t)d * 65 * 128;
        const int kb = (sg >> 2) * 32 + (sg & 3) * 4;
        #pragma unroll
        for (int i = 0; i < 4; ++i) {
            v[i]     = f2bf(W1d[(kb + i) * 128 + j]);
            v[i + 4] = f2bf(W1d[(kb + 16 + i) * 128 + j]);
        }
    } else {
        const int sg2 = sg - 8;
        const float* W2d = W2 + (size_t)d * 128 * 128;
        const int kb = (sg2 >> 2) * 32 + (sg2 & 3) * 4;
        #pragma unroll
        for (int i = 0; i < 4; ++i) {
            v[i]     = f2bf(W2d[(kb + i) * 128 + j]);
            v[i + 4] = f2bf(W2d[(kb + 16 + i) * 128 + j]);
        }
    }
    ws[(size_t)d * 24 * 128 + sg * 128 + j] = v;
}

// ---------------- main fused kernel ------------------------------------------
// Block = 256 thr = 4 waves, 128 edges (32/wave, es=2 x 16).
// Slab staged per-d from pre-converted ws via global_load_lds (no VALU).
// Small params LDS-resident for the whole block (R2-proven). k=64 passthrough
// folded into d1 init as fp32 FMA from LDS. launch_bounds(256,2): VGPR cap 256.
__global__ __launch_bounds__(256, 2)
void rape_mfma5_kernel(const float* __restrict__ source,
                       const float* __restrict__ target,
                       const int*   __restrict__ edge,
                       const float* __restrict__ freqs,
                       const float* __restrict__ W1,
                       const float* __restrict__ b1,
                       const float* __restrict__ ln_w,
                       const float* __restrict__ ln_b,
                       const float* __restrict__ b2,
                       const s16x8* __restrict__ wsg,
                       float* __restrict__ out)
{
    __shared__ s16x8 slab[24 * 128];      // 49152 B, restaged per d
    __shared__ float feat_s[6][128];      // 3072 B
    __shared__ float b1_s[768];           // [d][j]  3072 B
    __shared__ float lnw_s[768];
    __shared__ float lnb_s[768];
    __shared__ float w164_s[768];         // W1[d][64][j]
    __shared__ float freq_s[192];         // 768 B   -> total 65280 B

    const int tid   = threadIdx.x;
    const int lane  = tid & 63;
    const int wv    = tid >> 6;           // wave 0..3
    const int c     = lane & 15;          // edge-col within 16
    const int g     = lane >> 4;          // k-group 0..3
    const int ebase = blockIdx.x * 128;

    // ---- one-time staging: params + features ----
    for (int i = tid; i < 768; i += 256) {
        b1_s[i]   = b1[i];
        lnw_s[i]  = ln_w[i];
        lnb_s[i]  = ln_b[i];
        w164_s[i] = W1[((size_t)(i >> 7) * 65 + 64) * 128 + (i & 127)];
    }
    if (tid < 192) freq_s[tid] = freqs[tid];

    if (tid < 128) {
        int ec = ebase + tid; if (ec >= E_EDGES) ec = E_EDGES - 1;
        int si = edge[ec];
        int ti = edge[E_EDGES + ec];
        const float* S = source + (size_t)si * 5;
        const float* T = target + (size_t)ti * 5;
        float spx = S[0], spy = S[1], shd = S[2], ss = S[3];
        float tpx = T[0], tpy = T[1], thd = T[2], ts = T[3];
        float dx = spx - tpx, dy = spy - tpy;
        float dist = sqrtf(dx * dx + dy * dy);
        float ic  = dist < 3.0f ? 1.0f : 0.0f;
        float inv = dist > 0.0f ? 1.0f / dist : 0.0f;
        float ca  = dist > 0.0f ? dx * inv : 1.0f;   // cos(atan2), atan2(0,0)=0
        float sa  = dy * inv;
        float a = shd - thd + PI_F;
        float r = fmodf(a, TWOPI_F);
        r = r < 0.0f ? r + TWOPI_F : r;
        float dh = r - PI_F;
        float tc = ts * (cosf(thd) * ca + sinf(thd) * sa);
        float sc = ss * (cosf(shd) * ca + sinf(shd) * sa);
        feat_s[0][tid] = dx; feat_s[1][tid] = dy; feat_s[2][tid] = dh;
        feat_s[3][tid] = ic; feat_s[4][tid] = tc; feat_s[5][tid] = sc;
    }

    // ---- acc init: sum_d b2[d][g'],  g' = 4g + q + 16gt (global, once) ----
    f32x4 acc[2][8];
    #pragma unroll
    for (int gt = 0; gt < 8; ++gt) {
        f32x4 s = {0.f, 0.f, 0.f, 0.f};
        #pragma unroll
        for (int d = 0; d < 6; ++d)
            s += *(const f32x4*)(b2 + d * 128 + gt * 16 + g * 4);
        acc[0][gt] = s; acc[1][gt] = s;
    }

    for (int d = 0; d < 6; ++d) {
        __syncthreads();   // prev-d fragment reads done; d=0: params/feat visible

        // ---- stage this d's slab: 49152 B linear copy via global_load_lds ----
        {
            const char* gsrc = (const char*)(wsg + (size_t)d * 24 * 128);
            #pragma unroll
            for (int it = 0; it < 12; ++it) {
                const int off = tid * 16 + it * 4096;
                __builtin_amdgcn_global_load_lds(
                    (const __attribute__((address_space(1))) unsigned int*)(gsrc + off),
                    (__attribute__((address_space(3))) unsigned int*)((char*)slab + off),
                    16, 0, 0);
            }
        }

        // ---- m1 B-frags from trig while staging flies ----
        // k = 32*ks + 4g + q + 16p ; elem i<4 -> p=0, i>=4 -> p=1
        s16x8 bfr[2][2];
        float xv[2];
        const f32x4 fq0 = *(const f32x4*)(freq_s + d * 32 + g * 4);
        const f32x4 fq1 = *(const f32x4*)(freq_s + d * 32 + 16 + g * 4);
        #pragma unroll
        for (int es = 0; es < 2; ++es) {
            const float x = feat_s[d][wv * 32 + es * 16 + c];
            xv[es] = x;
            s16x8 bc, bs;
            #pragma unroll
            for (int i = 0; i < 8; ++i) {
                const float f = (i < 4) ? fq0[i] : fq1[i - 4];
                const float t = x * f;
                const float tf = t - floorf(t);
                bc[i] = f2bf(__builtin_amdgcn_cosf(tf));  // cos(2*pi*t)
                bs[i] = f2bf(__builtin_amdgcn_sinf(tf));
            }
            bfr[es][0] = bc; bfr[es][1] = bs;
        }

        // ---- d1 init: b1 + x * W1[k=64] (fp32 passthrough, from LDS) ----
        f32x4 d1[2][8];
        #pragma unroll
        for (int jt = 0; jt < 8; ++jt) {
            const f32x4 bv  = *(const f32x4*)(b1_s   + d * 128 + jt * 16 + g * 4);
            const f32x4 wv4 = *(const f32x4*)(w164_s + d * 128 + jt * 16 + g * 4);
            d1[0][jt] = bv + xv[0] * wv4;
            d1[1][jt] = bv + xv[1] * wv4;
        }

        __syncthreads();   // slab staged (vmcnt drained at barrier)

        // ---- m1: D1'[j][e] += sum_{k<64} W1^T[j][k] * X^T[k][e] ----
        #pragma unroll
        for (int jt = 0; jt < 8; ++jt) {
            const s16x8 a0 = slab[(0 + g) * 128 + jt * 16 + c];
            const s16x8 a1 = slab[(4 + g) * 128 + jt * 16 + c];
            #pragma unroll
            for (int es = 0; es < 2; ++es) {
                d1[es][jt] = __builtin_amdgcn_mfma_f32_16x16x32_bf16(a0, bfr[es][0], d1[es][jt], 0, 0, 0);
                d1[es][jt] = __builtin_amdgcn_mfma_f32_16x16x32_bf16(a1, bfr[es][1], d1[es][jt], 0, 0, 0);
            }
        }

        // ---- LayerNorm stats (lane holds j = 4g+q+16jt) ----
        float mu[2], rinv[2];
        #pragma unroll
        for (int es = 0; es < 2; ++es) {
            float s1 = 0.f, s2 = 0.f;
            #pragma unroll
            for (int jt = 0; jt < 8; ++jt)
                #pragma unroll
                for (int q = 0; q < 4; ++q) {
                    const float v = d1[es][jt][q];
                    s1 += v; s2 = fmaf(v, v, s2);
                }
            s1 += __shfl_xor(s1, 16); s1 += __shfl_xor(s1, 32);
            s2 += __shfl_xor(s2, 16); s2 += __shfl_xor(s2, 32);
            mu[es] = s1 * 0.0078125f;
            const float var = s2 * 0.0078125f - mu[es] * mu[es];
            rinv[es] = rsqrtf(var + 1e-5f);
        }
        // ---- LN apply + ReLU + pack (lw/lb read once, applied to both es) ----
        s16x8 pb[2][4];
        #pragma unroll
        for (int ks = 0; ks < 4; ++ks) {
            #pragma unroll
            for (int p = 0; p < 2; ++p) {
                const int jt = 2 * ks + p;
                const f32x4 lw = *(const f32x4*)(lnw_s + d * 128 + jt * 16 + g * 4);
                const f32x4 lb = *(const f32x4*)(lnb_s + d * 128 + jt * 16 + g * 4);
                #pragma unroll
                for (int es = 0; es < 2; ++es) {
                    #pragma unroll
                    for (int q = 0; q < 4; ++q) {
                        float hv = (d1[es][jt][q] - mu[es]) * rinv[es];
                        hv = fmaf(hv, lw[q], lb[q]);
                        hv = fmaxf(hv, 0.f);
                        pb[es][ks][q + 4 * p] = f2bf(hv);   // m2 B-frag (k=j)
                    }
                }
            }
        }

        // ---- m2: acc[g'][e] += sum_j W2^T[g'][j] * H'[j][e] ----
        #pragma unroll
        for (int gt = 0; gt < 8; ++gt) {
            const s16x8 a0 = slab[(8 + 0 * 4 + g) * 128 + gt * 16 + c];
            const s16x8 a1 = slab[(8 + 1 * 4 + g) * 128 + gt * 16 + c];
            const s16x8 a2 = slab[(8 + 2 * 4 + g) * 128 + gt * 16 + c];
            const s16x8 a3 = slab[(8 + 3 * 4 + g) * 128 + gt * 16 + c];
            #pragma unroll
            for (int es = 0; es < 2; ++es) {
                acc[es][gt] = __builtin_amdgcn_mfma_f32_16x16x32_bf16(a0, pb[es][0], acc[es][gt], 0, 0, 0);
                acc[es][gt] = __builtin_amdgcn_mfma_f32_16x16x32_bf16(a1, pb[es][1], acc[es][gt], 0, 0, 0);
                acc[es][gt] = __builtin_amdgcn_mfma_f32_16x16x32_bf16(a2, pb[es][2], acc[es][gt], 0, 0, 0);
                acc[es][gt] = __builtin_amdgcn_mfma_f32_16x16x32_bf16(a3, pb[es][3], acc[es][gt], 0, 0, 0);
            }
        }
    }

    // ---- store: lane holds g' = 4g + q + 16gt of edges (wv*32 + es*16 + c) ----
    #pragma unroll
    for (int es = 0; es < 2; ++es) {
        const int e = ebase + wv * 32 + es * 16 + c;
        if (e < E_EDGES) {
            float* op = out + (size_t)e * 128 + g * 4;
            #pragma unroll
            for (int gt = 0; gt < 8; ++gt)
                *(f32x4*)(op + gt * 16) = acc[es][gt];
        }
    }
}

extern "C" void kernel_launch(void* const* d_in, const int* in_sizes, int n_in,
                              void* d_out, int out_size, void* d_ws, size_t ws_size,
                              hipStream_t stream) {
    const float* source = (const float*)d_in[0];
    const float* target = (const float*)d_in[1];
    const int*   edge   = (const int*)  d_in[2];
    const float* freqs  = (const float*)d_in[3];
    const float* W1     = (const float*)d_in[4];
    const float* b1     = (const float*)d_in[5];
    const float* ln_w   = (const float*)d_in[6];
    const float* ln_b   = (const float*)d_in[7];
    const float* W2     = (const float*)d_in[8];
    const float* b2     = (const float*)d_in[9];
    float* out = (float*)d_out;
    s16x8* wsg = (s16x8*)d_ws;    // needs 6*24*128*16 = 294912 B

    rape_prep_kernel<<<6 * 24, 128, 0, stream>>>(W1, W2, wsg);

    const int nblocks = (E_EDGES + 127) / 128;  // 3907
    rape_mfma5_kernel<<<nblocks, 256, 0, stream>>>(
        source, target, edge, freqs, W1, b1, ln_w, ln_b, b2, wsg, out);
}